// Round 3
// baseline (171.718 us; speedup 1.0000x reference)
//
#include <hip/hip_runtime.h>

// Sinkhorn loss, single-pass moment formulation.
//   s_t = relu(v_t); X_t = cumsum(s); Sx = sum_t X_t
//   loss_p = sum_t t * (X_t/Sx - Y_t/Sy)^2 ;  out = sum_p loss_p
// Sub-chunk s (LCH=16 rows; local cumsum c; exclusive offset O_s):
//   contribution = g^2*T_s + 2g*(isx*pl - isy*pm) + isx^2*pll
//                  - 2*isx*isy*plm + isy^2*pmm,   g = isx*O - isy*P.
// R11: p2 LDS-transpose staging: 166.8 -> 155.8 us.
// R12: p1 register staging (MLP depth 64) = NULL (48 us invariant) ->
//      wave-level latency hiding is NOT the limiter. p3 folded into p2 (kept).
// R13 (this round): block-level stream contiguity. Old p1: each block walked
//      16KB row stride with 2KB contiguous pieces (512 interleaved strided
//      streams device-wide). New p1: CH=256 x LCH=16; one 1024-thread block
//      per sub-chunk reads a fully CONTIGUOUS 256KB span per array
//      (full 16KB rows, float4 per lane); 256 blocks = 1/CU, 16 waves/CU.
//      Per-element math statement-identical -> moments bitwise identical.
//      p2: per-lane merge of 4 consecutive sub-chunks (exact f64 offset
//      algebra), then the verified 64-lane scan/reduce; 5 paired LDS phases.

#define NT   4096
#define NP   4096
#define CH   256    // sub-chunks
#define LCH  16     // rows per sub-chunk; CH*LCH == NT
#define P1B  1024
#define SUB  4      // sub-chunks merged per p2 lane (SUB*64 == CH)

#define PCOLS 16    // columns per p2 block
#define PPAD  17    // LDS row stride (floats)

__global__ __launch_bounds__(P1B) void p1_moments(
    const float* __restrict__ x, const float* __restrict__ y,
    float* __restrict__ aX, float* __restrict__ aY,
    float* __restrict__ uL, float* __restrict__ uM,
    float* __restrict__ pL, float* __restrict__ pM,
    float* __restrict__ pLL, float* __restrict__ pMM,
    float* __restrict__ pLM,
    double* __restrict__ acc, unsigned* __restrict__ cnt)
{
  if (blockIdx.x == 0 && threadIdx.x == 0) { *acc = 0.0; *cnt = 0u; }

  const int j   = blockIdx.x;          // sub-chunk 0..255
  const int t0  = j * LCH;
  const int tid = threadIdx.x;         // owns columns 4*tid .. 4*tid+3
  const float4* xb = (const float4*)x + (size_t)t0 * (NP / 4) + tid;
  const float4* yb = (const float4*)y + (size_t)t0 * (NP / 4) + tid;

  float cx[4]  = {0.f,0.f,0.f,0.f}, cy[4]  = {0.f,0.f,0.f,0.f};
  float uLr[4] = {0.f,0.f,0.f,0.f}, uMr[4] = {0.f,0.f,0.f,0.f};
  float pLr[4] = {0.f,0.f,0.f,0.f}, pMr[4] = {0.f,0.f,0.f,0.f};
  float pLLr[4]= {0.f,0.f,0.f,0.f}, pMMr[4]= {0.f,0.f,0.f,0.f};
  float pLMr[4]= {0.f,0.f,0.f,0.f};

#pragma unroll 4
  for (int i = 0; i < LCH; ++i) {
    const float4 xv = xb[(size_t)i * (NP / 4)];
    const float4 yv = yb[(size_t)i * (NP / 4)];
    const float t = (float)(t0 + i);
#define P1STEP(e, xc, yc) { \
      const float lx = fmaxf((xc), 0.f), ly = fmaxf((yc), 0.f); \
      cx[e] += lx; cy[e] += ly; \
      const float tl = t * cx[e], tm = t * cy[e]; \
      pLr[e] += tl;                   pMr[e] += tm; \
      pLLr[e] = fmaf(tl, cx[e], pLLr[e]); \
      pMMr[e] = fmaf(tm, cy[e], pMMr[e]); \
      pLMr[e] = fmaf(tl, cy[e], pLMr[e]); \
      uLr[e] += cx[e];                uMr[e] += cy[e]; }
    P1STEP(0, xv.x, yv.x)
    P1STEP(1, xv.y, yv.y)
    P1STEP(2, xv.z, yv.z)
    P1STEP(3, xv.w, yv.w)
#undef P1STEP
  }

  const size_t o4 = (size_t)j * (NP / 4) + tid;
  ((float4*)aX)[o4]  = make_float4(cx[0],  cx[1],  cx[2],  cx[3]);
  ((float4*)aY)[o4]  = make_float4(cy[0],  cy[1],  cy[2],  cy[3]);
  ((float4*)uL)[o4]  = make_float4(uLr[0], uLr[1], uLr[2], uLr[3]);
  ((float4*)uM)[o4]  = make_float4(uMr[0], uMr[1], uMr[2], uMr[3]);
  ((float4*)pL)[o4]  = make_float4(pLr[0], pLr[1], pLr[2], pLr[3]);
  ((float4*)pM)[o4]  = make_float4(pMr[0], pMr[1], pMr[2], pMr[3]);
  ((float4*)pLL)[o4] = make_float4(pLLr[0],pLLr[1],pLLr[2],pLLr[3]);
  ((float4*)pMM)[o4] = make_float4(pMMr[0],pMMr[1],pMMr[2],pMMr[3]);
  ((float4*)pLM)[o4] = make_float4(pLMr[0],pLMr[1],pLMr[2],pLMr[3]);
}

// p2: block owns PCOLS=16 columns; 4 waves x 4 cols. Lane l merges its 4
// consecutive sub-chunks (rows 64l..64l+63) with exact f64 offset algebra,
// then the verified 64-lane scan/reduce. Five paired staging phases keep
// every global read a fully-used 64B line.
__global__ __launch_bounds__(256) void p2_loss(
    const float* __restrict__ aX, const float* __restrict__ aY,
    const float* __restrict__ uL, const float* __restrict__ uM,
    const float* __restrict__ pL, const float* __restrict__ pM,
    const float* __restrict__ pLL, const float* __restrict__ pMM,
    const float* __restrict__ pLM,
    double* __restrict__ acc, unsigned* __restrict__ cnt,
    float* __restrict__ out)
{
  __shared__ float s0[CH][PPAD];     // 17 KB
  __shared__ float s1[CH][PPAD];     // 17 KB
  __shared__ double sred[4];
  __shared__ int lastFlag;

  const int tid  = threadIdx.x;
  const int p0   = blockIdx.x * PCOLS;
  const int wave = tid >> 6;
  const int lane = tid & 63;
  const int q    = tid & 3;          // float4 slot within a 16-col row
  const int r0   = tid >> 2;         // base row 0..63

#define STAGE2(A, B) { \
    __syncthreads(); \
    for (int rr = 0; rr < 4; ++rr) { \
      const int r = r0 + 64 * rr; \
      const float4 va = *(const float4*)((A) + (size_t)r * NP + p0 + 4 * q); \
      s0[r][4*q+0] = va.x; s0[r][4*q+1] = va.y; \
      s0[r][4*q+2] = va.z; s0[r][4*q+3] = va.w; \
      const float4 vb = *(const float4*)((B) + (size_t)r * NP + p0 + 4 * q); \
      s1[r][4*q+0] = vb.x; s1[r][4*q+1] = vb.y; \
      s1[r][4*q+2] = vb.z; s1[r][4*q+3] = vb.w; \
    } \
    __syncthreads(); }

#define STAGE1(A) { \
    __syncthreads(); \
    for (int rr = 0; rr < 4; ++rr) { \
      const int r = r0 + 64 * rr; \
      const float4 va = *(const float4*)((A) + (size_t)r * NP + p0 + 4 * q); \
      s0[r][4*q+0] = va.x; s0[r][4*q+1] = va.y; \
      s0[r][4*q+2] = va.z; s0[r][4*q+3] = va.w; \
    } \
    __syncthreads(); }

  float  ax[4][SUB], ay[4][SUB];       // per-col per-sub a,b (f32 exact)
  float  plsub[4][SUB], pmsub[4][SUB];
  double O[4], P[4], isx[4], isy[4], loss[4];

  // ---- phase A: scan of sub-chunk totals -> exclusive lane offsets
  STAGE2(aX, aY);
#pragma unroll
  for (int c = 0; c < 4; ++c) {
    const int col = wave * 4 + c;
    double A = 0.0, B = 0.0;
#pragma unroll
    for (int k = 0; k < SUB; ++k) {
      ax[c][k] = s0[SUB * lane + k][col];
      ay[c][k] = s1[SUB * lane + k][col];
      A += (double)ax[c][k]; B += (double)ay[c][k];
    }
    double sx = A, sy = B;
    for (int d = 1; d < 64; d <<= 1) {
      const double tx = __shfl_up(sx, d, 64);
      const double ty = __shfl_up(sy, d, 64);
      if (lane >= d) { sx += tx; sy += ty; }
    }
    O[c] = sx - A; P[c] = sy - B;
  }

  // ---- phase U: totals Sx, Sy -> isx, isy ; start loss with g^2*Tj
  STAGE2(uL, uM);
#pragma unroll
  for (int c = 0; c < 4; ++c) {
    const int col = wave * 4 + c;
    double U = 0.0, V = 0.0, lx = 0.0, ly = 0.0;
#pragma unroll
    for (int k = 0; k < SUB; ++k) {
      U += (double)s0[SUB * lane + k][col] + 16.0 * lx;
      V += (double)s1[SUB * lane + k][col] + 16.0 * ly;
      lx += (double)ax[c][k]; ly += (double)ay[c][k];
    }
    double vx = 64.0 * O[c] + U;
    double vy = 64.0 * P[c] + V;
    for (int m = 32; m; m >>= 1) {
      vx += __shfl_xor(vx, m, 64);
      vy += __shfl_xor(vy, m, 64);
    }
    isx[c] = 1.0 / vx; isy[c] = 1.0 / vy;
    const double g = isx[c] * O[c] - isy[c] * P[c];
    loss[c] = g * g * (4096.0 * (double)lane + 2016.0);
  }

  // ---- phase pL/pM: first moments
  STAGE2(pL, pM);
#pragma unroll
  for (int c = 0; c < 4; ++c) {
    const int col = wave * 4 + c;
    double PLv = 0.0, PMv = 0.0, lx = 0.0, ly = 0.0;
#pragma unroll
    for (int k = 0; k < SUB; ++k) {
      const double Ts = 256.0 * (double)(SUB * lane + k) + 120.0;
      const float plk = s0[SUB * lane + k][col];
      const float pmk = s1[SUB * lane + k][col];
      plsub[c][k] = plk; pmsub[c][k] = pmk;
      PLv += (double)plk + lx * Ts;
      PMv += (double)pmk + ly * Ts;
      lx += (double)ax[c][k]; ly += (double)ay[c][k];
    }
    const double g = isx[c] * O[c] - isy[c] * P[c];
    loss[c] += 2.0 * g * (isx[c] * PLv - isy[c] * PMv);
  }

  // ---- phase pLL/pMM: pure second moments
  STAGE2(pLL, pMM);
#pragma unroll
  for (int c = 0; c < 4; ++c) {
    const int col = wave * 4 + c;
    double PLLv = 0.0, PMMv = 0.0, lx = 0.0, ly = 0.0;
#pragma unroll
    for (int k = 0; k < SUB; ++k) {
      const double Ts = 256.0 * (double)(SUB * lane + k) + 120.0;
      PLLv += (double)s0[SUB * lane + k][col]
            + 2.0 * lx * (double)plsub[c][k] + lx * lx * Ts;
      PMMv += (double)s1[SUB * lane + k][col]
            + 2.0 * ly * (double)pmsub[c][k] + ly * ly * Ts;
      lx += (double)ax[c][k]; ly += (double)ay[c][k];
    }
    loss[c] += isx[c] * isx[c] * PLLv + isy[c] * isy[c] * PMMv;
  }

  // ---- phase pLM: cross moment
  STAGE1(pLM);
#pragma unroll
  for (int c = 0; c < 4; ++c) {
    const int col = wave * 4 + c;
    double PLMv = 0.0, lx = 0.0, ly = 0.0;
#pragma unroll
    for (int k = 0; k < SUB; ++k) {
      const double Ts = 256.0 * (double)(SUB * lane + k) + 120.0;
      PLMv += (double)s0[SUB * lane + k][col]
            + lx * (double)pmsub[c][k] + ly * (double)plsub[c][k]
            + lx * ly * Ts;
      lx += (double)ax[c][k]; ly += (double)ay[c][k];
    }
    loss[c] += -2.0 * isx[c] * isy[c] * PLMv;
  }

  // ---- reduce and finish (device atomics; last block writes out)
  double L = (loss[0] + loss[1]) + (loss[2] + loss[3]);
  for (int m = 32; m; m >>= 1) L += __shfl_xor(L, m, 64);
  if (lane == 0) sred[wave] = L;
  __syncthreads();
  if (tid == 0) {
    const double btot = (sred[0] + sred[1]) + (sred[2] + sred[3]);
    atomicAdd(acc, btot);
    __threadfence();
    const unsigned old = atomicAdd(cnt, 1u);
    lastFlag = (old == gridDim.x - 1) ? 1 : 0;
  }
  __syncthreads();
  if (lastFlag && tid == 0) {
    const double tot = atomicAdd(acc, 0.0);
    out[0] = (float)tot;
  }
}

extern "C" void kernel_launch(void* const* d_in, const int* in_sizes, int n_in,
                              void* d_out, int out_size, void* d_ws, size_t ws_size,
                              hipStream_t stream) {
  const float* x = (const float*)d_in[0];
  const float* y = (const float*)d_in[1];
  float* out = (float*)d_out;

  const size_t CNP = (size_t)CH * NP;  // 1M floats = 4 MB per array
  char* ws = (char*)d_ws;
  float* aX  = (float*)ws; ws += CNP * sizeof(float);
  float* aY  = (float*)ws; ws += CNP * sizeof(float);
  float* uLp = (float*)ws; ws += CNP * sizeof(float);
  float* uMp = (float*)ws; ws += CNP * sizeof(float);
  float* pLp = (float*)ws; ws += CNP * sizeof(float);
  float* pMp = (float*)ws; ws += CNP * sizeof(float);
  float* pLLp = (float*)ws; ws += CNP * sizeof(float);
  float* pMMp = (float*)ws; ws += CNP * sizeof(float);
  float* pLMp = (float*)ws; ws += CNP * sizeof(float);
  double* acc = (double*)ws; ws += 64;
  unsigned* cnt = (unsigned*)ws; ws += 64;

  p1_moments<<<CH, P1B, 0, stream>>>(x, y, aX, aY, uLp, uMp, pLp, pMp,
                                     pLLp, pMMp, pLMp, acc, cnt);
  p2_loss<<<NP / PCOLS, 256, 0, stream>>>(aX, aY, uLp, uMp, pLp, pMp,
                                          pLLp, pMMp, pLMp, acc, cnt, out);
}

// Round 4
// 164.906 us; speedup vs baseline: 1.0413x; 1.0413x over previous
//
#include <hip/hip_runtime.h>

// Sinkhorn loss, single-pass moment formulation — FUSED single kernel.
//   s_t = relu(v_t); X_t = cumsum(s); Sx = sum_t X_t
//   loss_p = sum_t t * (X_t/Sx - Y_t/Sy)^2 ;  out = sum_p loss_p
// Chunk j (LCH=64 rows; local cumsums L,M; exclusive offsets O,P):
//   sum_{t in j} t*(isx*X - isy*Y)^2 = g^2*T_j + 2g*(isx*pL - isy*pM)
//        + isx^2*pLL - 2*isx*isy*pLM + isy^2*pMM,  g = isx*O - isy*P.
// Evidence ledger:
//   R11: p2 LDS-transpose staging: 166.8 -> 155.8 us.
//   R12: p1 register staging (MLP depth 64) NULL -> not latency-hiding-bound.
//   R13: contiguous 256KB block spans NULL on reads, +6us from 4x writes.
//   KEY: p1 time identical whether FETCH=65MB (HBM) or ~0 (L3-resident) ->
//   read path pinned at ~2.9-3.0 TB/s delivered regardless of source; every
//   CU-side knob (waves, width, MLP, contiguity, block shape) measured
//   invariant. p1 reads are at a fabric-path ceiling; stop optimizing them.
//   R14 (this round): eliminate everything AROUND the reads. One kernel:
//   block owns a 16-col strip for ALL t -> chunk moments never leave the
//   block (regs -> LDS [9][64][17], the R11-verified layout), scan phase is
//   the verified p2 body verbatim, intermediates (9.4MB write + 9.4MB read)
//   and the kernel-boundary gap disappear. 128B memset re-arms atomics.

#define NT   4096
#define NP   4096
#define CH   64     // chunks == scan-wave size
#define LCH  64     // rows per chunk
#define BLK  256    // 4 waves
#define PCOLS 16    // columns per block
#define PPAD  17    // LDS row stride (floats); odd -> conflict-free col reads

__global__ __launch_bounds__(BLK) void sink_fused(
    const float* __restrict__ x, const float* __restrict__ y,
    double* __restrict__ acc, unsigned* __restrict__ cnt,
    float* __restrict__ out)
{
  __shared__ float s[9][CH][PPAD];   // 38.25 KB
  __shared__ double sred[4];
  __shared__ int lastFlag;

  const int tid = threadIdx.x;
  const int p0  = blockIdx.x * PCOLS;
  const int j   = tid >> 2;          // chunk 0..63
  const int q   = tid & 3;           // quarter: cols p0+4q .. p0+4q+3
  const int t0  = j * LCH;

  // lanes 4j..4j+3 of a wave cover one full 64B line per row -> 100% line use
  const float4* xb = (const float4*)(x + (size_t)t0 * NP + p0 + 4 * q);
  const float4* yb = (const float4*)(y + (size_t)t0 * NP + p0 + 4 * q);

  float cx[4]  = {0.f,0.f,0.f,0.f}, cy[4]  = {0.f,0.f,0.f,0.f};
  float uLr[4] = {0.f,0.f,0.f,0.f}, uMr[4] = {0.f,0.f,0.f,0.f};
  float pLr[4] = {0.f,0.f,0.f,0.f}, pMr[4] = {0.f,0.f,0.f,0.f};
  float pLLr[4]= {0.f,0.f,0.f,0.f}, pMMr[4]= {0.f,0.f,0.f,0.f};
  float pLMr[4]= {0.f,0.f,0.f,0.f};

#pragma unroll 8
  for (int i = 0; i < LCH; ++i) {
    const float4 xv = xb[(size_t)i * (NP / 4)];
    const float4 yv = yb[(size_t)i * (NP / 4)];
    const float t = (float)(t0 + i);
#define P1STEP(e, xc, yc) { \
      const float lx = fmaxf((xc), 0.f), ly = fmaxf((yc), 0.f); \
      cx[e] += lx; cy[e] += ly; \
      const float tl = t * cx[e], tm = t * cy[e]; \
      pLr[e] += tl;                   pMr[e] += tm; \
      pLLr[e] = fmaf(tl, cx[e], pLLr[e]); \
      pMMr[e] = fmaf(tm, cy[e], pMMr[e]); \
      pLMr[e] = fmaf(tl, cy[e], pLMr[e]); \
      uLr[e] += cx[e];                uMr[e] += cy[e]; }
    P1STEP(0, xv.x, yv.x)
    P1STEP(1, xv.y, yv.y)
    P1STEP(2, xv.z, yv.z)
    P1STEP(3, xv.w, yv.w)
#undef P1STEP
  }

  // chunk moments -> LDS (compile-time indices only; fully unrolled)
#pragma unroll
  for (int e = 0; e < 4; ++e) {
    s[0][j][4*q+e] = cx[e];
    s[1][j][4*q+e] = cy[e];
    s[2][j][4*q+e] = uLr[e];
    s[3][j][4*q+e] = uMr[e];
    s[4][j][4*q+e] = pLr[e];
    s[5][j][4*q+e] = pMr[e];
    s[6][j][4*q+e] = pLLr[e];
    s[7][j][4*q+e] = pMMr[e];
    s[8][j][4*q+e] = pLMr[e];
  }
  __syncthreads();

  // ---- scan/loss phase: verified R11/R12 p2 body, verbatim ----
  const int wave = tid >> 6;           // 4 waves
  const int lane = tid & 63;           // = chunk j

  double wsum = 0.0;

#pragma unroll
  for (int c = 0; c < 4; ++c) {
    const int col = wave * 4 + c;

    const double a  = (double)s[0][lane][col];
    const double b  = (double)s[1][lane][col];
    const double ul = (double)s[2][lane][col];
    const double um = (double)s[3][lane][col];

    // inclusive scan -> exclusive offsets
    double sx = a, sy = b;
    for (int d = 1; d < 64; d <<= 1) {
      const double tx = __shfl_up(sx, d, 64);
      const double ty = __shfl_up(sy, d, 64);
      if (lane >= d) { sx += tx; sy += ty; }
    }
    const double O = sx - a;
    const double P = sy - b;

    // Sx = sum_j (LCH*O_j + uL_j), butterfly reduce (all lanes get total)
    double vx = (double)LCH * O + ul;
    double vy = (double)LCH * P + um;
    for (int m = 32; m; m >>= 1) {
      vx += __shfl_xor(vx, m, 64);
      vy += __shfl_xor(vy, m, 64);
    }
    const double isx = 1.0 / vx;
    const double isy = 1.0 / vy;

    const double g   = isx * O - isy * P;
    const double Tj  = 4096.0 * (double)lane + 2016.0;
    const double sh  = isx * (double)s[4][lane][col] - isy * (double)s[5][lane][col];
    const double shh = isx * isx * (double)s[6][lane][col]
                     - 2.0 * isx * isy * (double)s[8][lane][col]
                     + isy * isy * (double)s[7][lane][col];
    double loss = g * g * Tj + 2.0 * g * sh + shh;

    for (int m = 32; m; m >>= 1) loss += __shfl_xor(loss, m, 64);
    if (lane == 0) wsum += loss;
  }

  if (lane == 0) sred[wave] = wsum;
  __syncthreads();
  if (tid == 0) {
    const double btot = (sred[0] + sred[1]) + (sred[2] + sred[3]);
    atomicAdd(acc, btot);              // device-scope f64 atomic
    __threadfence();
    const unsigned old = atomicAdd(cnt, 1u);
    lastFlag = (old == gridDim.x - 1) ? 1 : 0;
  }
  __syncthreads();
  if (lastFlag && tid == 0) {
    const double tot = atomicAdd(acc, 0.0);  // atomic read at coherent point
    out[0] = (float)tot;
  }
}

extern "C" void kernel_launch(void* const* d_in, const int* in_sizes, int n_in,
                              void* d_out, int out_size, void* d_ws, size_t ws_size,
                              hipStream_t stream) {
  const float* x = (const float*)d_in[0];
  const float* y = (const float*)d_in[1];
  float* out = (float*)d_out;

  char* ws = (char*)d_ws;
  double* acc = (double*)ws;           // [0,8): f64 accumulator
  unsigned* cnt = (unsigned*)(ws + 64);// own cache line

  // re-arm the atomic control block each iteration (graph-capture-safe)
  hipMemsetAsync(ws, 0, 128, stream);

  sink_fused<<<NP / PCOLS, BLK, 0, stream>>>(x, y, acc, cnt, out);
}

// Round 5
// 163.916 us; speedup vs baseline: 1.0476x; 1.0060x over previous
//
#include <hip/hip_runtime.h>

// Sinkhorn loss, single-pass moment formulation — FUSED single kernel.
//   s_t = relu(v_t); X_t = cumsum(s); Sx = sum_t X_t
//   loss_p = sum_t t * (X_t/Sx - Y_t/Sy)^2 ;  out = sum_p loss_p
// Chunk j (LCH=64 rows; local cumsums L,M; exclusive offsets O,P):
//   sum_{t in j} t*(isx*X - isy*Y)^2 = g^2*T_j + 2g*(isx*pL - isy*pM)
//        + isx^2*pLL - 2*isx*isy*pLM + isy^2*pMM,  g = isx*O - isy*P.
// Evidence ledger:
//   R11: p2 LDS-transpose staging: 166.8 -> 155.8 us.
//   R12: p1 register staging (MLP depth 64) NULL -> not latency-bound per-wave.
//   R13: contiguous block spans NULL on reads; writes 4x = +6 us. Reads pinned
//        at ~2.9-3.0 TB/s delivered (identical time HBM vs L3-resident) ->
//        fill-path ceiling; all CU-side read knobs measured invariant.
//   R14: fused single kernel: intermediates+boundary gone, but 256 blocks x
//        4 waves @ 39KB LDS = 1 block/CU (4 waves/CU) -> kernel 66 us vs 48.
//        Residual overhead measured: total 164.9 - 66 = ~99 us (harness floor).
//   R15 (this round): same fusion at p1's occupancy. BLK=512 (8 waves),
//        2 cols/thread (float2), 2 blocks/CU (16 waves/CU), scan = 8 waves
//        x 2 cols. Read geometry still full-64B-line per row. Math identical.

#define NT   4096
#define NP   4096
#define CH   64     // chunks == scan-wave size
#define LCH  64     // rows per chunk
#define BLK  512    // 8 waves
#define PCOLS 16    // columns per block
#define PPAD  17    // LDS row stride (floats); odd -> conflict-free col reads

__global__ __launch_bounds__(BLK) void sink_fused(
    const float* __restrict__ x, const float* __restrict__ y,
    double* __restrict__ acc, unsigned* __restrict__ cnt,
    float* __restrict__ out)
{
  __shared__ float s[9][CH][PPAD];   // 38.25 KB -> 2 blocks/CU
  __shared__ double sred[8];
  __shared__ int lastFlag;

  const int tid = threadIdx.x;
  const int p0  = blockIdx.x * PCOLS;
  const int j   = tid >> 3;          // chunk 0..63
  const int q   = tid & 7;           // octant: cols p0+2q, p0+2q+1
  const int t0  = j * LCH;

  // 8 lanes x 8B cover one full 64B line per j-row per instruction
  const float2* xb = (const float2*)(x + (size_t)t0 * NP + p0 + 2 * q);
  const float2* yb = (const float2*)(y + (size_t)t0 * NP + p0 + 2 * q);

  float cx0 = 0.f, cx1 = 0.f, cy0 = 0.f, cy1 = 0.f;
  float uL0 = 0.f, uL1 = 0.f, uM0 = 0.f, uM1 = 0.f;
  float pL0 = 0.f, pL1 = 0.f, pM0 = 0.f, pM1 = 0.f;
  float pLL0 = 0.f, pLL1 = 0.f, pMM0 = 0.f, pMM1 = 0.f;
  float pLM0 = 0.f, pLM1 = 0.f;

#pragma unroll 8
  for (int i = 0; i < LCH; ++i) {
    const float2 xv = xb[(size_t)i * (NP / 2)];
    const float2 yv = yb[(size_t)i * (NP / 2)];
    const float t = (float)(t0 + i);

    const float lx0 = fmaxf(xv.x, 0.f), lx1 = fmaxf(xv.y, 0.f);
    const float ly0 = fmaxf(yv.x, 0.f), ly1 = fmaxf(yv.y, 0.f);

    cx0 += lx0; cy0 += ly0;
    const float tl0 = t * cx0, tm0 = t * cy0;
    pL0  += tl0;                  pM0  += tm0;
    pLL0 = fmaf(tl0, cx0, pLL0);  pMM0 = fmaf(tm0, cy0, pMM0);
    pLM0 = fmaf(tl0, cy0, pLM0);
    uL0  += cx0;                  uM0  += cy0;

    cx1 += lx1; cy1 += ly1;
    const float tl1 = t * cx1, tm1 = t * cy1;
    pL1  += tl1;                  pM1  += tm1;
    pLL1 = fmaf(tl1, cx1, pLL1);  pMM1 = fmaf(tm1, cy1, pMM1);
    pLM1 = fmaf(tl1, cy1, pLM1);
    uL1  += cx1;                  uM1  += cy1;
  }

  // chunk moments -> LDS (compile-time-unrolled indices)
  {
    const int c0 = 2 * q;
    s[0][j][c0] = cx0;  s[0][j][c0+1] = cx1;
    s[1][j][c0] = cy0;  s[1][j][c0+1] = cy1;
    s[2][j][c0] = uL0;  s[2][j][c0+1] = uL1;
    s[3][j][c0] = uM0;  s[3][j][c0+1] = uM1;
    s[4][j][c0] = pL0;  s[4][j][c0+1] = pL1;
    s[5][j][c0] = pM0;  s[5][j][c0+1] = pM1;
    s[6][j][c0] = pLL0; s[6][j][c0+1] = pLL1;
    s[7][j][c0] = pMM0; s[7][j][c0+1] = pMM1;
    s[8][j][c0] = pLM0; s[8][j][c0+1] = pLM1;
  }
  __syncthreads();

  // ---- scan/loss phase: verified body; 8 waves x 2 cols ----
  const int wave = tid >> 6;           // 0..7
  const int lane = tid & 63;           // = chunk j

  double wsum = 0.0;

#pragma unroll
  for (int c = 0; c < 2; ++c) {
    const int col = wave * 2 + c;

    const double a  = (double)s[0][lane][col];
    const double b  = (double)s[1][lane][col];
    const double ul = (double)s[2][lane][col];
    const double um = (double)s[3][lane][col];

    // inclusive scan -> exclusive offsets
    double sx = a, sy = b;
    for (int d = 1; d < 64; d <<= 1) {
      const double tx = __shfl_up(sx, d, 64);
      const double ty = __shfl_up(sy, d, 64);
      if (lane >= d) { sx += tx; sy += ty; }
    }
    const double O = sx - a;
    const double P = sy - b;

    // Sx = sum_j (LCH*O_j + uL_j), butterfly reduce (all lanes get total)
    double vx = (double)LCH * O + ul;
    double vy = (double)LCH * P + um;
    for (int m = 32; m; m >>= 1) {
      vx += __shfl_xor(vx, m, 64);
      vy += __shfl_xor(vy, m, 64);
    }
    const double isx = 1.0 / vx;
    const double isy = 1.0 / vy;

    const double g   = isx * O - isy * P;
    const double Tj  = 4096.0 * (double)lane + 2016.0;
    const double sh  = isx * (double)s[4][lane][col] - isy * (double)s[5][lane][col];
    const double shh = isx * isx * (double)s[6][lane][col]
                     - 2.0 * isx * isy * (double)s[8][lane][col]
                     + isy * isy * (double)s[7][lane][col];
    double loss = g * g * Tj + 2.0 * g * sh + shh;

    for (int m = 32; m; m >>= 1) loss += __shfl_xor(loss, m, 64);
    if (lane == 0) wsum += loss;
  }

  if (lane == 0) sred[wave] = wsum;
  __syncthreads();
  if (tid == 0) {
    const double btot = ((sred[0] + sred[1]) + (sred[2] + sred[3]))
                      + ((sred[4] + sred[5]) + (sred[6] + sred[7]));
    atomicAdd(acc, btot);              // device-scope f64 atomic
    __threadfence();
    const unsigned old = atomicAdd(cnt, 1u);
    lastFlag = (old == gridDim.x - 1) ? 1 : 0;
  }
  __syncthreads();
  if (lastFlag && tid == 0) {
    const double tot = atomicAdd(acc, 0.0);  // atomic read at coherent point
    out[0] = (float)tot;
  }
}

extern "C" void kernel_launch(void* const* d_in, const int* in_sizes, int n_in,
                              void* d_out, int out_size, void* d_ws, size_t ws_size,
                              hipStream_t stream) {
  const float* x = (const float*)d_in[0];
  const float* y = (const float*)d_in[1];
  float* out = (float*)d_out;

  char* ws = (char*)d_ws;
  double* acc = (double*)ws;            // [0,8): f64 accumulator
  unsigned* cnt = (unsigned*)(ws + 64); // own cache line

  // re-arm the atomic control block each iteration (graph-capture-safe)
  hipMemsetAsync(ws, 0, 128, stream);

  sink_fused<<<NP / PCOLS, BLK, 0, stream>>>(x, y, acc, cnt, out);
}

// Round 6
// 163.203 us; speedup vs baseline: 1.0522x; 1.0044x over previous
//
#include <hip/hip_runtime.h>

// Sinkhorn loss, single-pass moment formulation — best-measured structure
// (R1 two-kernel split) + p3 folded into p2 (R2 tail).
//   s_t = relu(v_t); X_t = cumsum(s); Sx = sum_t X_t
//   loss_p = sum_t t * (X_t/Sx - Y_t/Sy)^2 ;  out = sum_p loss_p
// Chunk j (LCH=64 rows; local cumsums L,M; exclusive offsets O,P):
//   sum_{t in j} t*(isx*X - isy*Y)^2 = g^2*T_j + 2g*(isx*pL - isy*pM)
//        + isx^2*pLL - 2*isx*isy*pLM + isy^2*pMM,  g = isx*O - isy*P.
// Evidence ledger:
//   R11: p2 LDS-transpose staging: 166.8 -> 155.8 us  (best measured).
//   R12: p1 register staging (MLP 64) NULL. p3->p2 fold proven correct.
//   R13: contiguous block spans NULL on reads (+6us from 4x writes).
//   R14/R15: full fusion = column-strip reads (64B granules @1MB stride,
//        serial scan tail at 1 blk/CU) -> 62.5us kernel, WORSE than 48+7.
//   CEILING MODEL (fits all rounds): unidirectional data path ~3.1-3.2 TB/s
//        (ubench "6.29 TB/s copy" = 3.15 read + 3.15 write, full duplex).
//        Read-only kernels cap at ~3; p1 @ 48us = 2.86 TB/s = ~90% of it.
//        Time identical for HBM-sourced vs L3-resident across all rounds.
//   R16: restore R1 kernels verbatim; keep only the p3-fold. Expect ~153-156.

#define NT   4096
#define NP   4096
#define CH   64     // number of t-chunks == wave size
#define LCH  64     // chunk length; CH*LCH == NT
#define BLK  256

#define PCOLS 16    // columns per p2 block
#define PPAD  17    // LDS row stride (floats); odd -> conflict-free col reads

__global__ __launch_bounds__(BLK) void p1_moments(
    const float* __restrict__ x, const float* __restrict__ y,
    float* __restrict__ aX, float* __restrict__ aY,
    float* __restrict__ uL, float* __restrict__ uM,
    float* __restrict__ pL, float* __restrict__ pM,
    float* __restrict__ pLL, float* __restrict__ pMM,
    float* __restrict__ pLM)
{
  const int pv = blockIdx.x * BLK + threadIdx.x;  // 0 .. NP/2-1 (float2 col)
  const int j  = blockIdx.y;
  const int t0 = j * LCH;
  const float2* xb = (const float2*)x + (size_t)t0 * (NP / 2) + pv;
  const float2* yb = (const float2*)y + (size_t)t0 * (NP / 2) + pv;

  float cx0 = 0.f, cx1 = 0.f, cy0 = 0.f, cy1 = 0.f;
  float uL0 = 0.f, uL1 = 0.f, uM0 = 0.f, uM1 = 0.f;
  float pL0 = 0.f, pL1 = 0.f, pM0 = 0.f, pM1 = 0.f;
  float pLL0 = 0.f, pLL1 = 0.f, pMM0 = 0.f, pMM1 = 0.f;
  float pLM0 = 0.f, pLM1 = 0.f;

#pragma unroll 8
  for (int i = 0; i < LCH; ++i) {
    const float2 xv = xb[(size_t)i * (NP / 2)];
    const float2 yv = yb[(size_t)i * (NP / 2)];
    const float t = (float)(t0 + i);

    const float lx0 = fmaxf(xv.x, 0.f), lx1 = fmaxf(xv.y, 0.f);
    const float ly0 = fmaxf(yv.x, 0.f), ly1 = fmaxf(yv.y, 0.f);

    cx0 += lx0; cy0 += ly0;
    const float tl0 = t * cx0, tm0 = t * cy0;
    pL0  += tl0;                  pM0  += tm0;
    pLL0 = fmaf(tl0, cx0, pLL0);  pMM0 = fmaf(tm0, cy0, pMM0);
    pLM0 = fmaf(tl0, cy0, pLM0);
    uL0  += cx0;                  uM0  += cy0;

    cx1 += lx1; cy1 += ly1;
    const float tl1 = t * cx1, tm1 = t * cy1;
    pL1  += tl1;                  pM1  += tm1;
    pLL1 = fmaf(tl1, cx1, pLL1);  pMM1 = fmaf(tm1, cy1, pMM1);
    pLM1 = fmaf(tl1, cy1, pLM1);
    uL1  += cx1;                  uM1  += cy1;
  }

  const size_t o2 = (size_t)j * (NP / 2) + pv;
  ((float2*)aX)[o2]  = make_float2(cx0, cx1);
  ((float2*)aY)[o2]  = make_float2(cy0, cy1);
  ((float2*)uL)[o2]  = make_float2(uL0, uL1);
  ((float2*)uM)[o2]  = make_float2(uM0, uM1);
  ((float2*)pL)[o2]  = make_float2(pL0, pL1);
  ((float2*)pM)[o2]  = make_float2(pM0, pM1);
  ((float2*)pLL)[o2] = make_float2(pLL0, pLL1);
  ((float2*)pMM)[o2] = make_float2(pMM0, pMM1);
  ((float2*)pLM)[o2] = make_float2(pLM0, pLM1);
}

// p2: block owns PCOLS=16 columns. Stage nine [64][16] tiles coalesced
// (float4 rows) into padded LDS; 4 waves x 4 cols run the verified
// double shuffle-scan. Tail: block total -> atomicAdd(acc); last block
// (arrival counter) reads acc atomically and writes float out.
__global__ __launch_bounds__(BLK) void p2_loss(
    const float* __restrict__ aX, const float* __restrict__ aY,
    const float* __restrict__ uL, const float* __restrict__ uM,
    const float* __restrict__ pL, const float* __restrict__ pM,
    const float* __restrict__ pLL, const float* __restrict__ pMM,
    const float* __restrict__ pLM,
    double* __restrict__ acc, unsigned* __restrict__ cnt,
    float* __restrict__ out)
{
  __shared__ float s[9][CH][PPAD];   // 9*64*17*4 = 38.25 KB
  __shared__ double sred[4];
  __shared__ int lastFlag;

  const int tid = threadIdx.x;
  const int p0  = blockIdx.x * PCOLS;

  // staging: tid -> (row j = tid>>2, float4 slot q = tid&3)
  {
    const int j = tid >> 2;        // 0..63
    const int q = tid & 3;         // 0..3
    const float* __restrict__ srcs[9] = {aX, aY, uL, uM, pL, pM, pLL, pMM, pLM};
#pragma unroll
    for (int a = 0; a < 9; ++a) {
      const float4 v = *(const float4*)(srcs[a] + (size_t)j * NP + p0 + 4 * q);
      s[a][j][4 * q + 0] = v.x;
      s[a][j][4 * q + 1] = v.y;
      s[a][j][4 * q + 2] = v.z;
      s[a][j][4 * q + 3] = v.w;
    }
  }
  __syncthreads();

  const int wave = tid >> 6;           // 4 waves per block
  const int lane = tid & 63;           // = chunk j

  double wsum = 0.0;                   // lane0-accumulated wave total

#pragma unroll
  for (int c = 0; c < 4; ++c) {
    const int col = wave * 4 + c;

    const double a  = (double)s[0][lane][col];
    const double b  = (double)s[1][lane][col];
    const double ul = (double)s[2][lane][col];
    const double um = (double)s[3][lane][col];

    // inclusive scan -> exclusive offsets
    double sx = a, sy = b;
    for (int d = 1; d < 64; d <<= 1) {
      const double tx = __shfl_up(sx, d, 64);
      const double ty = __shfl_up(sy, d, 64);
      if (lane >= d) { sx += tx; sy += ty; }
    }
    const double O = sx - a;
    const double P = sy - b;

    // Sx = sum_j (LCH*O_j + uL_j), butterfly reduce (all lanes get total)
    double vx = (double)LCH * O + ul;
    double vy = (double)LCH * P + um;
    for (int m = 32; m; m >>= 1) {
      vx += __shfl_xor(vx, m, 64);
      vy += __shfl_xor(vy, m, 64);
    }
    const double isx = 1.0 / vx;
    const double isy = 1.0 / vy;

    const double g   = isx * O - isy * P;
    const double Tj  = 4096.0 * (double)lane + 2016.0;
    const double sh  = isx * (double)s[4][lane][col] - isy * (double)s[5][lane][col];
    const double shh = isx * isx * (double)s[6][lane][col]
                     - 2.0 * isx * isy * (double)s[8][lane][col]
                     + isy * isy * (double)s[7][lane][col];
    double loss = g * g * Tj + 2.0 * g * sh + shh;

    for (int m = 32; m; m >>= 1) loss += __shfl_xor(loss, m, 64);
    if (lane == 0) wsum += loss;
  }

  if (lane == 0) sred[wave] = wsum;
  __syncthreads();
  if (tid == 0) {
    const double btot = (sred[0] + sred[1]) + (sred[2] + sred[3]);
    atomicAdd(acc, btot);              // device-scope f64 atomic
    __threadfence();
    const unsigned old = atomicAdd(cnt, 1u);
    lastFlag = (old == gridDim.x - 1) ? 1 : 0;
  }
  __syncthreads();
  if (lastFlag && tid == 0) {
    const double tot = atomicAdd(acc, 0.0);  // atomic read at coherent point
    out[0] = (float)tot;
  }
}

extern "C" void kernel_launch(void* const* d_in, const int* in_sizes, int n_in,
                              void* d_out, int out_size, void* d_ws, size_t ws_size,
                              hipStream_t stream) {
  const float* x = (const float*)d_in[0];
  const float* y = (const float*)d_in[1];
  float* out = (float*)d_out;

  const size_t CNP = (size_t)CH * NP;
  char* ws = (char*)d_ws;
  float* aX  = (float*)ws; ws += CNP * sizeof(float);
  float* aY  = (float*)ws; ws += CNP * sizeof(float);
  float* uLp = (float*)ws; ws += CNP * sizeof(float);
  float* uMp = (float*)ws; ws += CNP * sizeof(float);
  float* pLp = (float*)ws; ws += CNP * sizeof(float);
  float* pMp = (float*)ws; ws += CNP * sizeof(float);
  float* pLLp = (float*)ws; ws += CNP * sizeof(float);
  float* pMMp = (float*)ws; ws += CNP * sizeof(float);
  float* pLMp = (float*)ws; ws += CNP * sizeof(float);
  double* acc = (double*)ws; ws += 64;           // own cache line
  unsigned* cnt = (unsigned*)ws; ws += 64;

  // re-arm the atomic control block each iteration (graph-capture-safe)
  hipMemsetAsync(acc, 0, 128, stream);

  dim3 g1((NP / 2) / BLK, CH);  // 8 x 64 blocks, 2048 waves
  p1_moments<<<g1, BLK, 0, stream>>>(x, y, aX, aY, uLp, uMp, pLp, pMp,
                                     pLLp, pMMp, pLMp);
  p2_loss<<<NP / PCOLS, BLK, 0, stream>>>(aX, aY, uLp, uMp, pLp, pMp,
                                          pLLp, pMMp, pLMp, acc, cnt, out);
}